// Round 1
// baseline (390.178 us; speedup 1.0000x reference)
//
#include <hip/hip_runtime.h>

#define MIN_V 1e-7f
#define MAX_V 10.0f
#define INV15 (1.0f/15.0f)
#define CAP 32

static __device__ __forceinline__ float clipv(float v){
    return fminf(fmaxf(v, MIN_V), MAX_V);
}

// Build node -> (edge) incidence lists. One entry per (edge,slot) occurrence,
// so duplicate node indices inside an edge contribute twice (matches segment_sum).
__global__ void build_lists(const int* __restrict__ edges, int* __restrict__ cnt,
                            int* __restrict__ lists, int total){
    int i = blockIdx.x*256 + threadIdx.x;
    if (i >= total) return;
    int node = edges[i];
    int p = atomicAdd(&cnt[node], 1);
    if (p < CAP) lists[(size_t)node*CAP + p] = i >> 4;   // edge id
}

// ES1[e][d] = sum_s clip(H[idx_s][d])^2   (d = 0..127), one edge per 128-thread block
__global__ void es_l1(const float* __restrict__ H, const int* __restrict__ edges,
                      float* __restrict__ ES){
    int e = blockIdx.x;
    int d = threadIdx.x;
    const int* row = edges + (size_t)e*16;
    float es = 0.f;
    #pragma unroll
    for (int s=0;s<16;++s){
        float v = clipv(H[(size_t)row[s]*128 + d]);
        es += v*v;
    }
    ES[(size_t)e*128 + d] = es;
}

// Fused layer-1 node update: new = clip(H)+add, out = relu(rinv*(new@W1)+b1)
// wave-per-node; W1 kept in registers (32 per lane); 17-value butterfly reduce.
__global__ __launch_bounds__(256) void node_l1(
    const float* __restrict__ H, const float* __restrict__ ES,
    const int* __restrict__ cnt, const int* __restrict__ lists,
    const float* __restrict__ W1, const float* __restrict__ b1,
    float* __restrict__ X, int N){
    int wave = threadIdx.x >> 6, lane = threadIdx.x & 63;
    int d0 = lane, d1 = lane + 64;
    float w0[16], w1[16];
    #pragma unroll
    for (int h=0;h<16;++h){ w0[h] = W1[d0*16+h]; w1[h] = W1[d1*16+h]; }
    float bv = (lane < 16) ? b1[lane] : 0.f;

    for (int n = blockIdx.x*4 + wave; n < N; n += gridDim.x*4){
        float hc0 = clipv(H[(size_t)n*128 + d0]);
        float hc1 = clipv(H[(size_t)n*128 + d1]);
        float p0 = hc0*hc0, p1 = hc1*hc1;
        int len = cnt[n]; if (len > CAP) len = CAP;
        const int* lrow = lists + (size_t)n*CAP;
        float a0 = 0.f, a1 = 0.f;
        for (int k=0;k<len;++k){
            int e = lrow[k];
            float e0 = ES[(size_t)e*128 + d0];
            float e1 = ES[(size_t)e*128 + d1];
            a0 += sqrtf(fmaxf((e0 - p0)*INV15, 0.f));
            a1 += sqrtf(fmaxf((e1 - p1)*INV15, 0.f));
        }
        float n0 = hc0 + a0, n1 = hc1 + a1;
        float rs = n0 + n1;
        float acc[16];
        #pragma unroll
        for (int h=0;h<16;++h) acc[h] = n0*w0[h] + n1*w1[h];
        #pragma unroll
        for (int off=32; off>0; off>>=1){
            rs += __shfl_xor(rs, off, 64);
            #pragma unroll
            for (int h=0;h<16;++h) acc[h] += __shfl_xor(acc[h], off, 64);
        }
        float rinv = 1.0f / rs;
        float mine = acc[0];
        #pragma unroll
        for (int h=1;h<16;++h) mine = (lane == h) ? acc[h] : mine;
        if (lane < 16){
            float o = rinv*mine + bv;
            X[(size_t)n*16 + lane] = fmaxf(o, 0.f);
        }
    }
}

// ES2[e][d] = sum_s clip(X[idx_s][d])^2   (d = 0..15), 16 edges per 256-thread block
__global__ void es_l2(const float* __restrict__ X, const int* __restrict__ edges,
                      float* __restrict__ ES2, int E){
    int t = blockIdx.x*256 + threadIdx.x;
    int e = t >> 4, dd = t & 15;
    if (e >= E) return;
    const int* row = edges + (size_t)e*16;
    float es = 0.f;
    #pragma unroll
    for (int s=0;s<16;++s){
        float v = clipv(X[(size_t)row[s]*16 + dd]);
        es += v*v;
    }
    ES2[(size_t)e*16 + dd] = es;
}

// Fused layer-2 node update: thread-per-node, W2 from LDS, out = rinv*(new@W2)+b2
__global__ __launch_bounds__(256) void node_l2(
    const float* __restrict__ X, const float* __restrict__ ES2,
    const int* __restrict__ cnt, const int* __restrict__ lists,
    const float* __restrict__ W2, const float* __restrict__ b2,
    float* __restrict__ out, int N){
    __shared__ float sW[640];
    __shared__ float sb[40];
    for (int i=threadIdx.x;i<640;i+=256) sW[i] = W2[i];
    if (threadIdx.x < 40) sb[threadIdx.x] = b2[threadIdx.x];
    __syncthreads();
    int n = blockIdx.x*256 + threadIdx.x;
    if (n >= N) return;
    float xc[16], p[16], ad[16];
    #pragma unroll
    for (int d=0;d<16;++d){
        float v = clipv(X[(size_t)n*16+d]);
        xc[d]=v; p[d]=v*v; ad[d]=0.f;
    }
    int len = cnt[n]; if (len > CAP) len = CAP;
    const int* lrow = lists + (size_t)n*CAP;
    for (int k=0;k<len;++k){
        int e = lrow[k];
        #pragma unroll
        for (int d=0;d<16;++d){
            float es = ES2[(size_t)e*16+d];
            ad[d] += sqrtf(fmaxf((es - p[d])*INV15, 0.f));
        }
    }
    float rs = 0.f;
    float nw[16];
    #pragma unroll
    for (int d=0;d<16;++d){ nw[d] = xc[d] + ad[d]; rs += nw[d]; }
    float rinv = 1.0f / rs;
    float acc[40];
    #pragma unroll
    for (int c=0;c<40;++c) acc[c] = 0.f;
    #pragma unroll
    for (int d=0;d<16;++d){
        float v = nw[d];
        #pragma unroll
        for (int c=0;c<40;++c) acc[c] += v * sW[d*40+c];
    }
    #pragma unroll
    for (int c=0;c<40;++c)
        out[(size_t)n*40+c] = rinv*acc[c] + sb[c];
}

extern "C" void kernel_launch(void* const* d_in, const int* in_sizes, int n_in,
                              void* d_out, int out_size, void* d_ws, size_t ws_size,
                              hipStream_t stream){
    (void)n_in; (void)out_size; (void)ws_size;
    const float* H  = (const float*)d_in[0];
    const float* W1 = (const float*)d_in[1];
    const float* b1 = (const float*)d_in[2];
    const float* W2 = (const float*)d_in[3];
    const float* b2 = (const float*)d_in[4];
    const int* edges = (const int*)d_in[5];
    float* out = (float*)d_out;

    const int N = in_sizes[0] / 128;   // 200000
    const int E = in_sizes[5] / 16;    // 40000
    const int total = E * 16;          // 640000

    char* ws = (char*)d_ws;
    size_t off = 0;
    float* ES1 = (float*)(ws + off); off += (size_t)E*128*sizeof(float);  // 20.48 MB
    float* ES2 = (float*)(ws + off); off += (size_t)E*16*sizeof(float);   //  2.56 MB
    float* X1  = (float*)(ws + off); off += (size_t)N*16*sizeof(float);   // 12.80 MB
    int*   cnt = (int*)(ws + off);   off += (size_t)N*sizeof(int);        //  0.80 MB
    int* lists = (int*)(ws + off);   off += (size_t)N*CAP*sizeof(int);    // 25.60 MB

    hipMemsetAsync(cnt, 0, (size_t)N*sizeof(int), stream);
    build_lists<<<(total+255)/256, 256, 0, stream>>>(edges, cnt, lists, total);
    es_l1<<<E, 128, 0, stream>>>(H, edges, ES1);
    node_l1<<<2048, 256, 0, stream>>>(H, ES1, cnt, lists, W1, b1, X1, N);
    es_l2<<<(E*16+255)/256, 256, 0, stream>>>(X1, edges, ES2, E);
    node_l2<<<(N+255)/256, 256, 0, stream>>>(X1, ES2, cnt, lists, W2, b2, out, N);
}

// Round 2
// 281.649 us; speedup vs baseline: 1.3853x; 1.3853x over previous
//
#include <hip/hip_runtime.h>

#define MIN_V 1e-7f
#define MAX_V 10.0f
#define INV15 (1.0f/15.0f)
#define CAP 32

typedef _Float16 half4v __attribute__((ext_vector_type(4)));
typedef _Float16 half8v __attribute__((ext_vector_type(8)));

static __device__ __forceinline__ float clipv(float v){
    return fminf(fmaxf(v, MIN_V), MAX_V);
}

// Build node -> (edge) incidence lists. One entry per (edge,slot) occurrence,
// so duplicate node indices inside an edge contribute twice (matches segment_sum).
__global__ void build_lists(const int* __restrict__ edges, int* __restrict__ cnt,
                            int* __restrict__ lists, int total){
    int i = blockIdx.x*256 + threadIdx.x;
    if (i >= total) return;
    int node = edges[i];
    int p = atomicAdd(&cnt[node], 1);
    if (p < CAP) lists[(size_t)node*CAP + p] = i >> 4;   // edge id
}

// ES1[e][d] = sum_s clip(H[idx_s][d])^2   (d = 0..127), one edge per 128-thread block
__global__ void es_l1(const float* __restrict__ H, const int* __restrict__ edges,
                      float* __restrict__ ES){
    int e = blockIdx.x;
    int d = threadIdx.x;
    const int* row = edges + (size_t)e*16;
    float es = 0.f;
    #pragma unroll
    for (int s=0;s<16;++s){
        float v = clipv(H[(size_t)row[s]*128 + d]);
        es += v*v;
    }
    ES[(size_t)e*128 + d] = es;
}

// Layer-1 neighborhood aggregate, thread-per-(node, 4 dims).
// NEW1[n][d] = clip(H)[n][d] + sum_{e in inc(n)} sqrt((ES[e][d]-P[n][d])/15), fp16.
// Half-wave (32 lanes) covers one node's 128 dims -> ES row gathers are fully
// coalesced 512-B reads from the 20-MB L3-resident ES array; no shuffles.
__global__ __launch_bounds__(256) void gather_l1(
    const float* __restrict__ H, const float* __restrict__ ES,
    const int* __restrict__ cnt, const int* __restrict__ lists,
    _Float16* __restrict__ NEW1, int N){
    int t = blockIdx.x*256 + threadIdx.x;
    int n = t >> 5;
    if (n >= N) return;
    int dq = (t & 31) * 4;

    const float4 hv = *(const float4*)(H + (size_t)n*128 + dq);
    float h0 = clipv(hv.x), h1 = clipv(hv.y), h2 = clipv(hv.z), h3 = clipv(hv.w);
    float p0 = h0*h0, p1 = h1*h1, p2 = h2*h2, p3 = h3*h3;

    int len = cnt[n]; if (len > CAP) len = CAP;
    const int* lrow = lists + (size_t)n*CAP;
    float a0=0.f, a1=0.f, a2=0.f, a3=0.f;
    for (int k=0;k<len;++k){
        int e = lrow[k];
        const float4 es = *(const float4*)(ES + (size_t)e*128 + dq);
        a0 += sqrtf(fmaxf((es.x - p0)*INV15, 0.f));
        a1 += sqrtf(fmaxf((es.y - p1)*INV15, 0.f));
        a2 += sqrtf(fmaxf((es.z - p2)*INV15, 0.f));
        a3 += sqrtf(fmaxf((es.w - p3)*INV15, 0.f));
    }
    half4v o;
    o[0] = (_Float16)(h0 + a0);
    o[1] = (_Float16)(h1 + a1);
    o[2] = (_Float16)(h2 + a2);
    o[3] = (_Float16)(h3 + a3);
    *(half4v*)(NEW1 + (size_t)n*128 + dq) = o;
}

// Fused rowsum + [1x128]@[128x16] + bias + relu, wave-per-node.
// Lane = (q=lane>>4, h=lane&15): serial FMA over the q-th 32-dim quarter with
// W1 quarter-column in 32 registers; reduce = 2 xor-shuffles (not a 102-op butterfly).
__global__ __launch_bounds__(256) void gemm_l1(
    const _Float16* __restrict__ NEW1, const float* __restrict__ W1,
    const float* __restrict__ b1, float* __restrict__ X, int N){
    int wave = threadIdx.x >> 6, lane = threadIdx.x & 63;
    int q = lane >> 4, h = lane & 15;
    float w[32];
    #pragma unroll
    for (int i=0;i<32;++i) w[i] = W1[(q*32+i)*16 + h];
    float bv = b1[h];

    for (int n = blockIdx.x*4 + wave; n < N; n += gridDim.x*4){
        const half8v* row = (const half8v*)(NEW1 + (size_t)n*128 + q*32);
        float acc = 0.f, rs = 0.f;
        #pragma unroll
        for (int j=0;j<4;++j){
            half8v v = row[j];
            #pragma unroll
            for (int u=0;u<8;++u){
                float f = (float)v[u];
                acc += f * w[j*8+u];
                rs  += f;
            }
        }
        acc += __shfl_xor(acc, 16, 64);
        rs  += __shfl_xor(rs , 16, 64);
        acc += __shfl_xor(acc, 32, 64);
        rs  += __shfl_xor(rs , 32, 64);
        if (q == 0){
            float o = acc * (1.0f/rs) + bv;
            X[(size_t)n*16 + h] = fmaxf(o, 0.f);
        }
    }
}

// ES2[e][d] = sum_s clip(X[idx_s][d])^2   (d = 0..15), 16 edges per 256-thread block
__global__ void es_l2(const float* __restrict__ X, const int* __restrict__ edges,
                      float* __restrict__ ES2, int E){
    int t = blockIdx.x*256 + threadIdx.x;
    int e = t >> 4, dd = t & 15;
    if (e >= E) return;
    const int* row = edges + (size_t)e*16;
    float es = 0.f;
    #pragma unroll
    for (int s=0;s<16;++s){
        float v = clipv(X[(size_t)row[s]*16 + dd]);
        es += v*v;
    }
    ES2[(size_t)e*16 + dd] = es;
}

// Fused layer-2 node update: thread-per-node, W2 from LDS, out = rinv*(new@W2)+b2
__global__ __launch_bounds__(256) void node_l2(
    const float* __restrict__ X, const float* __restrict__ ES2,
    const int* __restrict__ cnt, const int* __restrict__ lists,
    const float* __restrict__ W2, const float* __restrict__ b2,
    float* __restrict__ out, int N){
    __shared__ float sW[640];
    __shared__ float sb[40];
    for (int i=threadIdx.x;i<640;i+=256) sW[i] = W2[i];
    if (threadIdx.x < 40) sb[threadIdx.x] = b2[threadIdx.x];
    __syncthreads();
    int n = blockIdx.x*256 + threadIdx.x;
    if (n >= N) return;
    float xc[16], p[16], ad[16];
    #pragma unroll
    for (int d=0;d<16;++d){
        float v = clipv(X[(size_t)n*16+d]);
        xc[d]=v; p[d]=v*v; ad[d]=0.f;
    }
    int len = cnt[n]; if (len > CAP) len = CAP;
    const int* lrow = lists + (size_t)n*CAP;
    for (int k=0;k<len;++k){
        int e = lrow[k];
        #pragma unroll
        for (int d=0;d<16;++d){
            float es = ES2[(size_t)e*16+d];
            ad[d] += sqrtf(fmaxf((es - p[d])*INV15, 0.f));
        }
    }
    float rs = 0.f;
    float nw[16];
    #pragma unroll
    for (int d=0;d<16;++d){ nw[d] = xc[d] + ad[d]; rs += nw[d]; }
    float rinv = 1.0f / rs;
    float acc[40];
    #pragma unroll
    for (int c=0;c<40;++c) acc[c] = 0.f;
    #pragma unroll
    for (int d=0;d<16;++d){
        float v = nw[d];
        #pragma unroll
        for (int c=0;c<40;++c) acc[c] += v * sW[d*40+c];
    }
    #pragma unroll
    for (int c=0;c<40;++c)
        out[(size_t)n*40+c] = rinv*acc[c] + sb[c];
}

extern "C" void kernel_launch(void* const* d_in, const int* in_sizes, int n_in,
                              void* d_out, int out_size, void* d_ws, size_t ws_size,
                              hipStream_t stream){
    (void)n_in; (void)out_size; (void)ws_size;
    const float* H  = (const float*)d_in[0];
    const float* W1 = (const float*)d_in[1];
    const float* b1 = (const float*)d_in[2];
    const float* W2 = (const float*)d_in[3];
    const float* b2 = (const float*)d_in[4];
    const int* edges = (const int*)d_in[5];
    float* out = (float*)d_out;

    const int N = in_sizes[0] / 128;   // 200000
    const int E = in_sizes[5] / 16;    // 40000
    const int total = E * 16;          // 640000

    char* ws = (char*)d_ws;
    size_t off = 0;
    float* ES1 = (float*)(ws + off); off += (size_t)E*128*sizeof(float);  // 20.48 MB
    float* ES2 = (float*)(ws + off); off += (size_t)E*16*sizeof(float);   //  2.56 MB
    float* X1  = (float*)(ws + off); off += (size_t)N*16*sizeof(float);   // 12.80 MB
    int*   cnt = (int*)(ws + off);   off += (size_t)N*sizeof(int);        //  0.80 MB
    int* lists = (int*)(ws + off);   off += (size_t)N*CAP*sizeof(int);    // 25.60 MB
    _Float16* NEW1 = (_Float16*)(ws + off); off += (size_t)N*128*sizeof(_Float16); // 51.20 MB

    hipMemsetAsync(cnt, 0, (size_t)N*sizeof(int), stream);
    build_lists<<<(total+255)/256, 256, 0, stream>>>(edges, cnt, lists, total);
    es_l1<<<E, 128, 0, stream>>>(H, edges, ES1);
    gather_l1<<<(N*32+255)/256, 256, 0, stream>>>(H, ES1, cnt, lists, NEW1, N);
    gemm_l1<<<2048, 256, 0, stream>>>(NEW1, W1, b1, X1, N);
    es_l2<<<(E*16+255)/256, 256, 0, stream>>>(X1, edges, ES2, E);
    node_l2<<<(N+255)/256, 256, 0, stream>>>(X1, ES2, cnt, lists, W2, b2, out, N);
}

// Round 3
// 245.520 us; speedup vs baseline: 1.5892x; 1.1472x over previous
//
#include <hip/hip_runtime.h>

#define MIN_V 1e-7f
#define MAX_V 10.0f
#define INV15 (1.0f/15.0f)
#define CAP 32

typedef _Float16 half2v __attribute__((ext_vector_type(2)));
typedef _Float16 half4v __attribute__((ext_vector_type(4)));
typedef _Float16 half8v __attribute__((ext_vector_type(8)));

static __device__ __forceinline__ float clipv(float v){
    return fminf(fmaxf(v, MIN_V), MAX_V);
}
static __device__ __forceinline__ float rsqrt_arg(float v){   // sqrt(max(v,0)), raw HW sqrt (~1 ulp)
    return __builtin_amdgcn_sqrtf(fmaxf(v, 0.f));
}

// CH[i] = fp16(clip(H[i])), 8 elements/thread streaming pass
__global__ __launch_bounds__(256) void ch_kernel(const float* __restrict__ H,
                                                 _Float16* __restrict__ CH, int total8){
    int i = blockIdx.x*256 + threadIdx.x;
    if (i >= total8) return;
    const float4* p = (const float4*)(H + (size_t)i*8);
    float4 a = p[0], b = p[1];
    half8v o;
    o[0]=(_Float16)clipv(a.x); o[1]=(_Float16)clipv(a.y);
    o[2]=(_Float16)clipv(a.z); o[3]=(_Float16)clipv(a.w);
    o[4]=(_Float16)clipv(b.x); o[5]=(_Float16)clipv(b.y);
    o[6]=(_Float16)clipv(b.z); o[7]=(_Float16)clipv(b.w);
    *(half8v*)(CH + (size_t)i*8) = o;
}

// node -> edge incidence lists (ushort edge ids; one 64B line per node)
__global__ void build_lists(const int* __restrict__ edges, int* __restrict__ cnt,
                            unsigned short* __restrict__ lists, int total){
    int i = blockIdx.x*256 + threadIdx.x;
    if (i >= total) return;
    int node = edges[i];
    int p = atomicAdd(&cnt[node], 1);
    if (p < CAP) lists[(size_t)node*CAP + p] = (unsigned short)(i >> 4);
}

// ES1s[e][d] = (1/15) * sum_s CH[idx_s][d]^2, fp16. Wave per edge, lane = 2 dims.
__global__ __launch_bounds__(256) void es_l1(const _Float16* __restrict__ CH,
                                             const int* __restrict__ edges,
                                             _Float16* __restrict__ ES1s, int E){
    int wave = threadIdx.x >> 6, lane = threadIdx.x & 63;
    int e = blockIdx.x*4 + wave;
    if (e >= E) return;
    const int* row = edges + (size_t)e*16;
    float s0 = 0.f, s1 = 0.f;
    #pragma unroll
    for (int s=0;s<16;++s){
        half2v v = *(const half2v*)(CH + (size_t)row[s]*128 + lane*2);
        float f0 = (float)v[0], f1 = (float)v[1];
        s0 += f0*f0; s1 += f1*f1;
    }
    half2v o; o[0] = (_Float16)(s0*INV15); o[1] = (_Float16)(s1*INV15);
    *(half2v*)(ES1s + (size_t)e*128 + lane*2) = o;
}

// Layer-1 aggregate: NEW1[n][d] = CH[n][d] + sum_e sqrt(ES1s[e][d] - CH^2/15)
// thread per (node, 4 dims); half-wave = one node, gathers are 256B coalesced rows.
__global__ __launch_bounds__(256) void gather_l1(
    const _Float16* __restrict__ CH, const _Float16* __restrict__ ES1s,
    const int* __restrict__ cnt, const unsigned short* __restrict__ lists,
    _Float16* __restrict__ NEW1, int N){
    int t = blockIdx.x*256 + threadIdx.x;
    int n = t >> 5;
    if (n >= N) return;
    int dq = (t & 31) * 4;

    half4v hv = *(const half4v*)(CH + (size_t)n*128 + dq);
    float h0=(float)hv[0], h1=(float)hv[1], h2=(float)hv[2], h3=(float)hv[3];
    float p0=h0*h0*INV15, p1=h1*h1*INV15, p2=h2*h2*INV15, p3=h3*h3*INV15;

    int len = cnt[n]; if (len > CAP) len = CAP;
    const unsigned short* lrow = lists + (size_t)n*CAP;
    float a0=0.f, a1=0.f, a2=0.f, a3=0.f;
    for (int k=0;k<len;++k){
        int e = lrow[k];
        half4v es = *(const half4v*)(ES1s + (size_t)e*128 + dq);
        a0 += rsqrt_arg((float)es[0] - p0);
        a1 += rsqrt_arg((float)es[1] - p1);
        a2 += rsqrt_arg((float)es[2] - p2);
        a3 += rsqrt_arg((float)es[3] - p3);
    }
    half4v o;
    o[0]=(_Float16)(h0+a0); o[1]=(_Float16)(h1+a1);
    o[2]=(_Float16)(h2+a2); o[3]=(_Float16)(h3+a3);
    *(half4v*)(NEW1 + (size_t)n*128 + dq) = o;
}

// rowsum + [1x128]@[128x16] + bias + relu, wave-per-node, X stored fp16
__global__ __launch_bounds__(256) void gemm_l1(
    const _Float16* __restrict__ NEW1, const float* __restrict__ W1,
    const float* __restrict__ b1, _Float16* __restrict__ X, int N){
    int wave = threadIdx.x >> 6, lane = threadIdx.x & 63;
    int q = lane >> 4, h = lane & 15;
    float w[32];
    #pragma unroll
    for (int i=0;i<32;++i) w[i] = W1[(q*32+i)*16 + h];
    float bv = b1[h];

    for (int n = blockIdx.x*4 + wave; n < N; n += gridDim.x*4){
        const half8v* row = (const half8v*)(NEW1 + (size_t)n*128 + q*32);
        float acc = 0.f, rs = 0.f;
        #pragma unroll
        for (int j=0;j<4;++j){
            half8v v = row[j];
            #pragma unroll
            for (int u=0;u<8;++u){
                float f = (float)v[u];
                acc += f * w[j*8+u];
                rs  += f;
            }
        }
        acc += __shfl_xor(acc, 16, 64);
        rs  += __shfl_xor(rs , 16, 64);
        acc += __shfl_xor(acc, 32, 64);
        rs  += __shfl_xor(rs , 32, 64);
        if (q == 0){
            float o = acc * __builtin_amdgcn_rcpf(rs) + bv;
            X[(size_t)n*16 + h] = (_Float16)fmaxf(o, 0.f);
        }
    }
}

// ES2s[e][d] = (1/15) * sum_s clip(X[idx_s][d])^2, f32. Thread per (edge, 2 dims).
__global__ __launch_bounds__(256) void es_l2(const _Float16* __restrict__ X,
                                             const int* __restrict__ edges,
                                             float* __restrict__ ES2s, int E){
    int t = blockIdx.x*256 + threadIdx.x;
    int e = t >> 3, dd2 = (t & 7)*2;
    if (e >= E) return;
    const int* row = edges + (size_t)e*16;
    float s0 = 0.f, s1 = 0.f;
    #pragma unroll
    for (int s=0;s<16;++s){
        half2v v = *(const half2v*)(X + (size_t)row[s]*16 + dd2);
        float f0 = clipv((float)v[0]), f1 = clipv((float)v[1]);
        s0 += f0*f0; s1 += f1*f1;
    }
    ES2s[(size_t)e*16 + dd2]     = s0*INV15;
    ES2s[(size_t)e*16 + dd2 + 1] = s1*INV15;
}

// Layer-2 fused node update: thread-per-node, W2 from LDS
__global__ __launch_bounds__(256) void node_l2(
    const _Float16* __restrict__ X, const float* __restrict__ ES2s,
    const int* __restrict__ cnt, const unsigned short* __restrict__ lists,
    const float* __restrict__ W2, const float* __restrict__ b2,
    float* __restrict__ out, int N){
    __shared__ float sW[640];
    __shared__ float sb[40];
    for (int i=threadIdx.x;i<640;i+=256) sW[i] = W2[i];
    if (threadIdx.x < 40) sb[threadIdx.x] = b2[threadIdx.x];
    __syncthreads();
    int n = blockIdx.x*256 + threadIdx.x;
    if (n >= N) return;
    float xc[16], ps[16], ad[16];
    const half8v* xr = (const half8v*)(X + (size_t)n*16);
    half8v x0 = xr[0], x1 = xr[1];
    #pragma unroll
    for (int d=0;d<8;++d){
        float v = clipv((float)x0[d]);
        xc[d]=v; ps[d]=v*v*INV15; ad[d]=0.f;
    }
    #pragma unroll
    for (int d=0;d<8;++d){
        float v = clipv((float)x1[d]);
        xc[8+d]=v; ps[8+d]=v*v*INV15; ad[8+d]=0.f;
    }
    int len = cnt[n]; if (len > CAP) len = CAP;
    const unsigned short* lrow = lists + (size_t)n*CAP;
    for (int k=0;k<len;++k){
        int e = lrow[k];
        const float4* er = (const float4*)(ES2s + (size_t)e*16);
        #pragma unroll
        for (int j=0;j<4;++j){
            float4 es = er[j];
            ad[j*4+0] += rsqrt_arg(es.x - ps[j*4+0]);
            ad[j*4+1] += rsqrt_arg(es.y - ps[j*4+1]);
            ad[j*4+2] += rsqrt_arg(es.z - ps[j*4+2]);
            ad[j*4+3] += rsqrt_arg(es.w - ps[j*4+3]);
        }
    }
    float rs = 0.f;
    float nw[16];
    #pragma unroll
    for (int d=0;d<16;++d){ nw[d] = xc[d] + ad[d]; rs += nw[d]; }
    float rinv = __builtin_amdgcn_rcpf(rs);
    float acc[40];
    #pragma unroll
    for (int c=0;c<40;++c) acc[c] = 0.f;
    #pragma unroll
    for (int d=0;d<16;++d){
        float v = nw[d];
        #pragma unroll
        for (int c=0;c<40;++c) acc[c] += v * sW[d*40+c];
    }
    float4 ob[10];
    #pragma unroll
    for (int c=0;c<40;++c) ((float*)ob)[c] = rinv*acc[c] + sb[c];
    float4* op = (float4*)(out + (size_t)n*40);
    #pragma unroll
    for (int j=0;j<10;++j) op[j] = ob[j];
}

extern "C" void kernel_launch(void* const* d_in, const int* in_sizes, int n_in,
                              void* d_out, int out_size, void* d_ws, size_t ws_size,
                              hipStream_t stream){
    (void)n_in; (void)out_size; (void)ws_size;
    const float* H  = (const float*)d_in[0];
    const float* W1 = (const float*)d_in[1];
    const float* b1 = (const float*)d_in[2];
    const float* W2 = (const float*)d_in[3];
    const float* b2 = (const float*)d_in[4];
    const int* edges = (const int*)d_in[5];
    float* out = (float*)d_out;

    const int N = in_sizes[0] / 128;   // 200000
    const int E = in_sizes[5] / 16;    // 40000
    const int total = E * 16;          // 640000

    char* ws = (char*)d_ws;
    size_t off = 0;
    // region A: CH (live until gather_l1), later reused for X + ES2s
    _Float16* CH = (_Float16*)(ws + off);
    _Float16* X  = (_Float16*)(ws + off);                       //  6.40 MB (over CH)
    float* ES2s  = (float*)(ws + off + (size_t)N*16*sizeof(_Float16)); // 2.56 MB
    off += (size_t)N*128*sizeof(_Float16);                      // 51.20 MB
    _Float16* ES1s = (_Float16*)(ws + off); off += (size_t)E*128*sizeof(_Float16); // 10.24 MB
    _Float16* NEW1 = (_Float16*)(ws + off); off += (size_t)N*128*sizeof(_Float16); // 51.20 MB
    int* cnt = (int*)(ws + off); off += (size_t)N*sizeof(int);  //  0.80 MB
    unsigned short* lists = (unsigned short*)(ws + off);
    off += (size_t)N*CAP*sizeof(unsigned short);                // 12.80 MB  (peak ~126 MB)

    hipMemsetAsync(cnt, 0, (size_t)N*sizeof(int), stream);
    ch_kernel<<<(N*128/8+255)/256, 256, 0, stream>>>(H, CH, N*128/8);
    build_lists<<<(total+255)/256, 256, 0, stream>>>(edges, cnt, lists, total);
    es_l1<<<(E+3)/4, 256, 0, stream>>>(CH, edges, ES1s, E);
    gather_l1<<<(N*32+255)/256, 256, 0, stream>>>(CH, ES1s, cnt, lists, NEW1, N);
    gemm_l1<<<2048, 256, 0, stream>>>(NEW1, W1, b1, X, N);
    es_l2<<<(E*8+255)/256, 256, 0, stream>>>(X, edges, ES2s, E);
    node_l2<<<(N+255)/256, 256, 0, stream>>>(X, ES2s, cnt, lists, W2, b2, out, N);
}

// Round 4
// 215.597 us; speedup vs baseline: 1.8098x; 1.1388x over previous
//
#include <hip/hip_runtime.h>

#define MIN_V 1e-7f
#define MAX_V 10.0f
#define INV15 (1.0f/15.0f)
#define CAP 32

typedef _Float16 half2v __attribute__((ext_vector_type(2)));
typedef _Float16 half4v __attribute__((ext_vector_type(4)));
typedef _Float16 half8v __attribute__((ext_vector_type(8)));

static __device__ __forceinline__ float clipv(float v){
    return fminf(fmaxf(v, MIN_V), MAX_V);
}
static __device__ __forceinline__ float rsqrt_arg(float v){   // sqrt(max(v,0)), raw HW sqrt (~1 ulp)
    return __builtin_amdgcn_sqrtf(fmaxf(v, 0.f));
}

// Fused: CH[i]=fp16(clip(H[i])) streaming pass + incidence-list build (independent work).
__global__ __launch_bounds__(256) void ch_build(
    const float* __restrict__ H, _Float16* __restrict__ CH, int total8,
    const int* __restrict__ edges, int* __restrict__ cnt,
    unsigned short* __restrict__ lists, int total){
    int i = blockIdx.x*256 + threadIdx.x;
    if (i < total8){
        const float4* p = (const float4*)(H + (size_t)i*8);
        float4 a = p[0], b = p[1];
        half8v o;
        o[0]=(_Float16)clipv(a.x); o[1]=(_Float16)clipv(a.y);
        o[2]=(_Float16)clipv(a.z); o[3]=(_Float16)clipv(a.w);
        o[4]=(_Float16)clipv(b.x); o[5]=(_Float16)clipv(b.y);
        o[6]=(_Float16)clipv(b.z); o[7]=(_Float16)clipv(b.w);
        *(half8v*)(CH + (size_t)i*8) = o;
    }
    if (i < total){
        int node = edges[i];
        int p = atomicAdd(&cnt[node], 1);
        if (p < CAP) lists[(size_t)node*CAP + p] = (unsigned short)(i >> 4);
    }
}

// ES1s[e][d] = (1/15) * sum_s CH[idx_s][d]^2, fp16. Wave per edge, lane = 2 dims.
// Node ids preloaded one-per-lane and broadcast via shfl -> all 16 gathers independent.
__global__ __launch_bounds__(256) void es_l1(const _Float16* __restrict__ CH,
                                             const int* __restrict__ edges,
                                             _Float16* __restrict__ ES1s, int E){
    int wave = threadIdx.x >> 6, lane = threadIdx.x & 63;
    int e = blockIdx.x*4 + wave;
    if (e >= E) return;
    int rid = edges[(size_t)e*16 + (lane & 15)];   // lane s holds node id s (dup x4)
    float s0 = 0.f, s1 = 0.f;
    #pragma unroll
    for (int s=0;s<16;++s){
        int idx = __shfl(rid, s, 64);
        half2v v = *(const half2v*)(CH + (size_t)idx*128 + lane*2);
        float f0 = (float)v[0], f1 = (float)v[1];
        s0 += f0*f0; s1 += f1*f1;
    }
    half2v o; o[0] = (_Float16)(s0*INV15); o[1] = (_Float16)(s1*INV15);
    *(half2v*)(ES1s + (size_t)e*128 + lane*2) = o;
}

// Layer-1 aggregate: NEW1[n][d] = CH[n][d] + sum_e sqrt(ES1s[e][d] - CH^2/15).
// Half-wave (32 lanes) per node, 4 dims/lane. Lane k preloads incidence entry k
// (whole 64-B list row in one transaction); edge loop unrolled x4 with
// unconditional gathers + masked accumulate -> 4 gathers in flight.
__global__ __launch_bounds__(256) void gather_l1(
    const _Float16* __restrict__ CH, const _Float16* __restrict__ ES1s,
    const int* __restrict__ cnt, const unsigned short* __restrict__ lists,
    _Float16* __restrict__ NEW1, int N){
    int t = blockIdx.x*256 + threadIdx.x;
    int n = t >> 5;
    if (n >= N) return;
    int k32 = t & 31;
    int dq = k32 * 4;

    int myid = (int)lists[(size_t)n*CAP + k32];    // lane k holds edge id k
    int len = cnt[n]; if (len > CAP) len = CAP;

    half4v hv = *(const half4v*)(CH + (size_t)n*128 + dq);
    float h0=(float)hv[0], h1=(float)hv[1], h2=(float)hv[2], h3=(float)hv[3];
    float p0=h0*h0*INV15, p1=h1*h1*INV15, p2=h2*h2*INV15, p3=h3*h3*INV15;

    float a0=0.f, a1=0.f, a2=0.f, a3=0.f;
    for (int k0=0;k0<len;k0+=4){
        int e0 = __shfl(myid, k0+0, 32);
        int e1 = __shfl(myid, k0+1, 32);
        int e2 = __shfl(myid, k0+2, 32);
        int e3 = __shfl(myid, k0+3, 32);
        half4v v0 = *(const half4v*)(ES1s + (size_t)e0*128 + dq);
        half4v v1 = *(const half4v*)(ES1s + (size_t)e1*128 + dq);
        half4v v2 = *(const half4v*)(ES1s + (size_t)e2*128 + dq);
        half4v v3 = *(const half4v*)(ES1s + (size_t)e3*128 + dq);
        // k0+0 always < len by loop condition
        a0 += rsqrt_arg((float)v0[0] - p0);
        a1 += rsqrt_arg((float)v0[1] - p1);
        a2 += rsqrt_arg((float)v0[2] - p2);
        a3 += rsqrt_arg((float)v0[3] - p3);
        bool m1 = (k0+1 < len), m2 = (k0+2 < len), m3 = (k0+3 < len);
        a0 += m1 ? rsqrt_arg((float)v1[0] - p0) : 0.f;
        a1 += m1 ? rsqrt_arg((float)v1[1] - p1) : 0.f;
        a2 += m1 ? rsqrt_arg((float)v1[2] - p2) : 0.f;
        a3 += m1 ? rsqrt_arg((float)v1[3] - p3) : 0.f;
        a0 += m2 ? rsqrt_arg((float)v2[0] - p0) : 0.f;
        a1 += m2 ? rsqrt_arg((float)v2[1] - p1) : 0.f;
        a2 += m2 ? rsqrt_arg((float)v2[2] - p2) : 0.f;
        a3 += m2 ? rsqrt_arg((float)v2[3] - p3) : 0.f;
        a0 += m3 ? rsqrt_arg((float)v3[0] - p0) : 0.f;
        a1 += m3 ? rsqrt_arg((float)v3[1] - p1) : 0.f;
        a2 += m3 ? rsqrt_arg((float)v3[2] - p2) : 0.f;
        a3 += m3 ? rsqrt_arg((float)v3[3] - p3) : 0.f;
    }
    half4v o;
    o[0]=(_Float16)(h0+a0); o[1]=(_Float16)(h1+a1);
    o[2]=(_Float16)(h2+a2); o[3]=(_Float16)(h3+a3);
    *(half4v*)(NEW1 + (size_t)n*128 + dq) = o;
}

// rowsum + [1x128]@[128x16] + bias + relu, wave-per-node, X stored fp16
__global__ __launch_bounds__(256) void gemm_l1(
    const _Float16* __restrict__ NEW1, const float* __restrict__ W1,
    const float* __restrict__ b1, _Float16* __restrict__ X, int N){
    int wave = threadIdx.x >> 6, lane = threadIdx.x & 63;
    int q = lane >> 4, h = lane & 15;
    float w[32];
    #pragma unroll
    for (int i=0;i<32;++i) w[i] = W1[(q*32+i)*16 + h];
    float bv = b1[h];

    for (int n = blockIdx.x*4 + wave; n < N; n += gridDim.x*4){
        const half8v* row = (const half8v*)(NEW1 + (size_t)n*128 + q*32);
        float acc = 0.f, rs = 0.f;
        #pragma unroll
        for (int j=0;j<4;++j){
            half8v v = row[j];
            #pragma unroll
            for (int u=0;u<8;++u){
                float f = (float)v[u];
                acc += f * w[j*8+u];
                rs  += f;
            }
        }
        acc += __shfl_xor(acc, 16, 64);
        rs  += __shfl_xor(rs , 16, 64);
        acc += __shfl_xor(acc, 32, 64);
        rs  += __shfl_xor(rs , 32, 64);
        if (q == 0){
            float o = acc * __builtin_amdgcn_rcpf(rs) + bv;
            X[(size_t)n*16 + h] = (_Float16)fmaxf(o, 0.f);
        }
    }
}

// ES2s[e][d] = (1/15) * sum_s clip(X[idx_s][d])^2, fp16. Thread per (edge, 2 dims).
__global__ __launch_bounds__(256) void es_l2(const _Float16* __restrict__ X,
                                             const int* __restrict__ edges,
                                             _Float16* __restrict__ ES2s, int E){
    int t = blockIdx.x*256 + threadIdx.x;
    int e = t >> 3, dd2 = (t & 7)*2;
    if (e >= E) return;
    const int* row = edges + (size_t)e*16;
    float s0 = 0.f, s1 = 0.f;
    #pragma unroll
    for (int s=0;s<16;++s){
        half2v v = *(const half2v*)(X + (size_t)row[s]*16 + dd2);
        float f0 = clipv((float)v[0]), f1 = clipv((float)v[1]);
        s0 += f0*f0; s1 += f1*f1;
    }
    half2v o; o[0]=(_Float16)(s0*INV15); o[1]=(_Float16)(s1*INV15);
    *(half2v*)(ES2s + (size_t)e*16 + dd2) = o;
}

// Layer-2 fused node update: thread-per-node, W2 from LDS, unroll-2 masked edge loop
__global__ __launch_bounds__(256) void node_l2(
    const _Float16* __restrict__ X, const _Float16* __restrict__ ES2s,
    const int* __restrict__ cnt, const unsigned short* __restrict__ lists,
    const float* __restrict__ W2, const float* __restrict__ b2,
    float* __restrict__ out, int N){
    __shared__ float sW[640];
    __shared__ float sb[40];
    for (int i=threadIdx.x;i<640;i+=256) sW[i] = W2[i];
    if (threadIdx.x < 40) sb[threadIdx.x] = b2[threadIdx.x];
    __syncthreads();
    int n = blockIdx.x*256 + threadIdx.x;
    if (n >= N) return;
    float xc[16], ps[16], ad[16];
    const half8v* xr = (const half8v*)(X + (size_t)n*16);
    half8v x0 = xr[0], x1 = xr[1];
    #pragma unroll
    for (int d=0;d<8;++d){
        float v = clipv((float)x0[d]);
        xc[d]=v; ps[d]=v*v*INV15; ad[d]=0.f;
    }
    #pragma unroll
    for (int d=0;d<8;++d){
        float v = clipv((float)x1[d]);
        xc[8+d]=v; ps[8+d]=v*v*INV15; ad[8+d]=0.f;
    }
    int len = cnt[n]; if (len > CAP) len = CAP;
    const unsigned short* lrow = lists + (size_t)n*CAP;
    for (int k0=0;k0<len;k0+=2){
        int e0 = lrow[k0];
        int e1 = (k0+1 < len) ? lrow[k0+1] : e0;
        bool m1 = (k0+1 < len);
        const half8v* r0 = (const half8v*)(ES2s + (size_t)e0*16);
        const half8v* r1 = (const half8v*)(ES2s + (size_t)e1*16);
        half8v ea0 = r0[0], eb0 = r0[1];
        half8v ea1 = r1[0], eb1 = r1[1];
        #pragma unroll
        for (int d=0;d<8;++d){
            ad[d]   += rsqrt_arg((float)ea0[d] - ps[d]);
            ad[8+d] += rsqrt_arg((float)eb0[d] - ps[8+d]);
        }
        #pragma unroll
        for (int d=0;d<8;++d){
            ad[d]   += m1 ? rsqrt_arg((float)ea1[d] - ps[d])   : 0.f;
            ad[8+d] += m1 ? rsqrt_arg((float)eb1[d] - ps[8+d]) : 0.f;
        }
    }
    float rs = 0.f;
    float nw[16];
    #pragma unroll
    for (int d=0;d<16;++d){ nw[d] = xc[d] + ad[d]; rs += nw[d]; }
    float rinv = __builtin_amdgcn_rcpf(rs);
    float acc[40];
    #pragma unroll
    for (int c=0;c<40;++c) acc[c] = 0.f;
    #pragma unroll
    for (int d=0;d<16;++d){
        float v = nw[d];
        #pragma unroll
        for (int c=0;c<40;++c) acc[c] += v * sW[d*40+c];
    }
    float4 ob[10];
    #pragma unroll
    for (int c=0;c<40;++c) ((float*)ob)[c] = rinv*acc[c] + sb[c];
    float4* op = (float4*)(out + (size_t)n*40);
    #pragma unroll
    for (int j=0;j<10;++j) op[j] = ob[j];
}

extern "C" void kernel_launch(void* const* d_in, const int* in_sizes, int n_in,
                              void* d_out, int out_size, void* d_ws, size_t ws_size,
                              hipStream_t stream){
    (void)n_in; (void)out_size; (void)ws_size;
    const float* H  = (const float*)d_in[0];
    const float* W1 = (const float*)d_in[1];
    const float* b1 = (const float*)d_in[2];
    const float* W2 = (const float*)d_in[3];
    const float* b2 = (const float*)d_in[4];
    const int* edges = (const int*)d_in[5];
    float* out = (float*)d_out;

    const int N = in_sizes[0] / 128;   // 200000
    const int E = in_sizes[5] / 16;    // 40000
    const int total = E * 16;          // 640000
    const int total8 = N * 128 / 8;    // 3.2M

    char* ws = (char*)d_ws;
    size_t off = 0;
    // region A: CH (live until gather_l1), later reused for X + ES2s
    _Float16* CH   = (_Float16*)(ws + off);
    _Float16* X    = (_Float16*)(ws + off);                              //  6.40 MB (over CH)
    _Float16* ES2s = (_Float16*)(ws + off + (size_t)N*16*sizeof(_Float16)); // 1.28 MB
    off += (size_t)N*128*sizeof(_Float16);                               // 51.20 MB
    _Float16* ES1s = (_Float16*)(ws + off); off += (size_t)E*128*sizeof(_Float16); // 10.24 MB
    _Float16* NEW1 = (_Float16*)(ws + off); off += (size_t)N*128*sizeof(_Float16); // 51.20 MB
    int* cnt = (int*)(ws + off); off += (size_t)N*sizeof(int);           //  0.80 MB
    unsigned short* lists = (unsigned short*)(ws + off);
    off += (size_t)N*CAP*sizeof(unsigned short);                         // 12.80 MB

    hipMemsetAsync(cnt, 0, (size_t)N*sizeof(int), stream);
    ch_build<<<(total8+255)/256, 256, 0, stream>>>(H, CH, total8, edges, cnt, lists, total);
    es_l1<<<(E+3)/4, 256, 0, stream>>>(CH, edges, ES1s, E);
    gather_l1<<<(N*32+255)/256, 256, 0, stream>>>(CH, ES1s, cnt, lists, NEW1, N);
    gemm_l1<<<2048, 256, 0, stream>>>(NEW1, W1, b1, X, N);
    es_l2<<<(E*8+255)/256, 256, 0, stream>>>(X, edges, ES2s, E);
    node_l2<<<(N+255)/256, 256, 0, stream>>>(X, ES2s, cnt, lists, W2, b2, out, N);
}

// Round 5
// 196.962 us; speedup vs baseline: 1.9810x; 1.0946x over previous
//
#include <hip/hip_runtime.h>

#define MIN_V 1e-7f
#define MAX_V 10.0f
#define INV15 (1.0f/15.0f)
#define CAP 32

typedef _Float16 half2v __attribute__((ext_vector_type(2)));
typedef _Float16 half4v __attribute__((ext_vector_type(4)));
typedef _Float16 half8v __attribute__((ext_vector_type(8)));

static __device__ __forceinline__ float clipv(float v){
    return fminf(fmaxf(v, MIN_V), MAX_V);
}
static __device__ __forceinline__ float rsqrt_arg(float v){   // sqrt(max(v,0)), raw HW sqrt (~1 ulp)
    return __builtin_amdgcn_sqrtf(fmaxf(v, 0.f));
}

// Pure streaming pass: CH[i] = fp16(clip(H[i])), grid-stride, 8 elems/thread/iter
__global__ __launch_bounds__(256) void ch_stream(const float* __restrict__ H,
                                                 _Float16* __restrict__ CH, int total8){
    int stride = gridDim.x*256;
    for (int i = blockIdx.x*256 + threadIdx.x; i < total8; i += stride){
        const float4* p = (const float4*)(H + (size_t)i*8);
        float4 a = p[0], b = p[1];
        half8v o;
        o[0]=(_Float16)clipv(a.x); o[1]=(_Float16)clipv(a.y);
        o[2]=(_Float16)clipv(a.z); o[3]=(_Float16)clipv(a.w);
        o[4]=(_Float16)clipv(b.x); o[5]=(_Float16)clipv(b.y);
        o[6]=(_Float16)clipv(b.z); o[7]=(_Float16)clipv(b.w);
        *(half8v*)(CH + (size_t)i*8) = o;
    }
}

// node -> edge incidence lists (ushort edge ids; one 64B line per node)
__global__ void build_lists(const int* __restrict__ edges, int* __restrict__ cnt,
                            unsigned short* __restrict__ lists, int total){
    int i = blockIdx.x*256 + threadIdx.x;
    if (i >= total) return;
    int node = edges[i];
    int p = atomicAdd(&cnt[node], 1);
    if (p < CAP) lists[(size_t)node*CAP + p] = (unsigned short)(i >> 4);
}

// ES1s[e][d] = (1/15) * sum_s CH[idx_s][d]^2, fp16. Wave per edge, lane = 2 dims.
// Node ids preloaded one-per-lane and broadcast via shfl -> all 16 gathers independent.
__global__ __launch_bounds__(256) void es_l1(const _Float16* __restrict__ CH,
                                             const int* __restrict__ edges,
                                             _Float16* __restrict__ ES1s, int E){
    int wave = threadIdx.x >> 6, lane = threadIdx.x & 63;
    int e = blockIdx.x*4 + wave;
    if (e >= E) return;
    int rid = edges[(size_t)e*16 + (lane & 15)];   // lane s holds node id s (dup x4)
    float s0 = 0.f, s1 = 0.f;
    #pragma unroll
    for (int s=0;s<16;++s){
        int idx = __shfl(rid, s, 64);
        half2v v = *(const half2v*)(CH + (size_t)idx*128 + lane*2);
        float f0 = (float)v[0], f1 = (float)v[1];
        s0 += f0*f0; s1 += f1*f1;
    }
    half2v o; o[0] = (_Float16)(s0*INV15); o[1] = (_Float16)(s1*INV15);
    *(half2v*)(ES1s + (size_t)e*128 + lane*2) = o;
}

// Fused layer-1: gather (half-wave per node, unroll-4 masked) -> LDS -> gemm
// (wave per node, W1 in registers). Eliminates the NEW1 global round-trip.
// LDS layout: snw[node][q*36 + i] f32 (quarter stride 36 -> b128-aligned,
// bank = (16*node + 4q + 4j) % 32, conflict-free across q at read time).
__global__ __launch_bounds__(256) void fused_l1(
    const _Float16* __restrict__ CH, const _Float16* __restrict__ ES1s,
    const int* __restrict__ cnt, const unsigned short* __restrict__ lists,
    const float* __restrict__ W1, const float* __restrict__ b1,
    _Float16* __restrict__ X, int N){
    __shared__ float snw[8*144];
    int tid = threadIdx.x;
    int wave = tid >> 6, lane = tid & 63;

    // phase-2 weight preload (once): lane (q,h) holds W1[q*32+i][h]
    int q = lane >> 4, h = lane & 15;
    float w[32];
    #pragma unroll
    for (int i=0;i<32;++i) w[i] = W1[(q*32+i)*16 + h];
    float bv = b1[h];

    int hw = tid >> 5;        // half-wave id 0..7
    int k32 = tid & 31;
    int dq = k32 * 4;

    int nb = blockIdx.x * 8;

    // ---- phase 1: gather node nb+hw ----
    int n = nb + hw;
    if (n < N){
        int myid = (int)lists[(size_t)n*CAP + k32];    // lane k holds edge id k
        int len = cnt[n]; if (len > CAP) len = CAP;

        half4v hv = *(const half4v*)(CH + (size_t)n*128 + dq);
        float h0=(float)hv[0], h1=(float)hv[1], h2=(float)hv[2], h3=(float)hv[3];
        float p0=h0*h0*INV15, p1=h1*h1*INV15, p2=h2*h2*INV15, p3=h3*h3*INV15;

        float a0=0.f, a1=0.f, a2=0.f, a3=0.f;
        for (int k0=0;k0<len;k0+=4){
            int e0 = __shfl(myid, k0+0, 32);
            int e1 = __shfl(myid, k0+1, 32);
            int e2 = __shfl(myid, k0+2, 32);
            int e3 = __shfl(myid, k0+3, 32);
            half4v v0 = *(const half4v*)(ES1s + (size_t)e0*128 + dq);
            half4v v1 = *(const half4v*)(ES1s + (size_t)e1*128 + dq);
            half4v v2 = *(const half4v*)(ES1s + (size_t)e2*128 + dq);
            half4v v3 = *(const half4v*)(ES1s + (size_t)e3*128 + dq);
            a0 += rsqrt_arg((float)v0[0] - p0);
            a1 += rsqrt_arg((float)v0[1] - p1);
            a2 += rsqrt_arg((float)v0[2] - p2);
            a3 += rsqrt_arg((float)v0[3] - p3);
            bool m1 = (k0+1 < len), m2 = (k0+2 < len), m3 = (k0+3 < len);
            a0 += m1 ? rsqrt_arg((float)v1[0] - p0) : 0.f;
            a1 += m1 ? rsqrt_arg((float)v1[1] - p1) : 0.f;
            a2 += m1 ? rsqrt_arg((float)v1[2] - p2) : 0.f;
            a3 += m1 ? rsqrt_arg((float)v1[3] - p3) : 0.f;
            a0 += m2 ? rsqrt_arg((float)v2[0] - p0) : 0.f;
            a1 += m2 ? rsqrt_arg((float)v2[1] - p1) : 0.f;
            a2 += m2 ? rsqrt_arg((float)v2[2] - p2) : 0.f;
            a3 += m2 ? rsqrt_arg((float)v2[3] - p3) : 0.f;
            a0 += m3 ? rsqrt_arg((float)v3[0] - p0) : 0.f;
            a1 += m3 ? rsqrt_arg((float)v3[1] - p1) : 0.f;
            a2 += m3 ? rsqrt_arg((float)v3[2] - p2) : 0.f;
            a3 += m3 ? rsqrt_arg((float)v3[3] - p3) : 0.f;
        }
        float4 wv;
        wv.x = h0+a0; wv.y = h1+a1; wv.z = h2+a2; wv.w = h3+a3;
        *(float4*)&snw[hw*144 + (k32>>3)*36 + (k32&7)*4] = wv;
    }
    __syncthreads();

    // ---- phase 2: wave handles nodes nb+wave*2 .. +1 ----
    #pragma unroll
    for (int r=0;r<2;++r){
        int nl = wave*2 + r;
        int n2 = nb + nl;
        if (n2 >= N) continue;
        float acc = 0.f, rs = 0.f;
        #pragma unroll
        for (int j=0;j<8;++j){
            float4 v = *(const float4*)&snw[nl*144 + q*36 + j*4];
            acc += v.x*w[j*4+0] + v.y*w[j*4+1] + v.z*w[j*4+2] + v.w*w[j*4+3];
            rs  += v.x + v.y + v.z + v.w;
        }
        acc += __shfl_xor(acc, 16, 64);
        rs  += __shfl_xor(rs , 16, 64);
        acc += __shfl_xor(acc, 32, 64);
        rs  += __shfl_xor(rs , 32, 64);
        if (q == 0){
            float o = acc * __builtin_amdgcn_rcpf(rs) + bv;
            X[(size_t)n2*16 + h] = (_Float16)fmaxf(o, 0.f);
        }
    }
}

// ES2s[e][d] = (1/15) * sum_s clip(X[idx_s][d])^2, fp16. Thread per (edge, 2 dims).
__global__ __launch_bounds__(256) void es_l2(const _Float16* __restrict__ X,
                                             const int* __restrict__ edges,
                                             _Float16* __restrict__ ES2s, int E){
    int t = blockIdx.x*256 + threadIdx.x;
    int e = t >> 3, dd2 = (t & 7)*2;
    if (e >= E) return;
    const int* row = edges + (size_t)e*16;
    float s0 = 0.f, s1 = 0.f;
    #pragma unroll
    for (int s=0;s<16;++s){
        half2v v = *(const half2v*)(X + (size_t)row[s]*16 + dd2);
        float f0 = clipv((float)v[0]), f1 = clipv((float)v[1]);
        s0 += f0*f0; s1 += f1*f1;
    }
    half2v o; o[0]=(_Float16)(s0*INV15); o[1]=(_Float16)(s1*INV15);
    *(half2v*)(ES2s + (size_t)e*16 + dd2) = o;
}

// Layer-2 fused node update: thread-per-node, W2 from LDS, unroll-2 masked edge loop
__global__ __launch_bounds__(256) void node_l2(
    const _Float16* __restrict__ X, const _Float16* __restrict__ ES2s,
    const int* __restrict__ cnt, const unsigned short* __restrict__ lists,
    const float* __restrict__ W2, const float* __restrict__ b2,
    float* __restrict__ out, int N){
    __shared__ float sW[640];
    __shared__ float sb[40];
    for (int i=threadIdx.x;i<640;i+=256) sW[i] = W2[i];
    if (threadIdx.x < 40) sb[threadIdx.x] = b2[threadIdx.x];
    __syncthreads();
    int n = blockIdx.x*256 + threadIdx.x;
    if (n >= N) return;
    float xc[16], ps[16], ad[16];
    const half8v* xr = (const half8v*)(X + (size_t)n*16);
    half8v x0 = xr[0], x1 = xr[1];
    #pragma unroll
    for (int d=0;d<8;++d){
        float v = clipv((float)x0[d]);
        xc[d]=v; ps[d]=v*v*INV15; ad[d]=0.f;
    }
    #pragma unroll
    for (int d=0;d<8;++d){
        float v = clipv((float)x1[d]);
        xc[8+d]=v; ps[8+d]=v*v*INV15; ad[8+d]=0.f;
    }
    int len = cnt[n]; if (len > CAP) len = CAP;
    const unsigned short* lrow = lists + (size_t)n*CAP;
    for (int k0=0;k0<len;k0+=2){
        int e0 = lrow[k0];
        int e1 = (k0+1 < len) ? lrow[k0+1] : e0;
        bool m1 = (k0+1 < len);
        const half8v* r0 = (const half8v*)(ES2s + (size_t)e0*16);
        const half8v* r1 = (const half8v*)(ES2s + (size_t)e1*16);
        half8v ea0 = r0[0], eb0 = r0[1];
        half8v ea1 = r1[0], eb1 = r1[1];
        #pragma unroll
        for (int d=0;d<8;++d){
            ad[d]   += rsqrt_arg((float)ea0[d] - ps[d]);
            ad[8+d] += rsqrt_arg((float)eb0[d] - ps[8+d]);
        }
        #pragma unroll
        for (int d=0;d<8;++d){
            ad[d]   += m1 ? rsqrt_arg((float)ea1[d] - ps[d])   : 0.f;
            ad[8+d] += m1 ? rsqrt_arg((float)eb1[d] - ps[8+d]) : 0.f;
        }
    }
    float rs = 0.f;
    float nw[16];
    #pragma unroll
    for (int d=0;d<16;++d){ nw[d] = xc[d] + ad[d]; rs += nw[d]; }
    float rinv = __builtin_amdgcn_rcpf(rs);
    float acc[40];
    #pragma unroll
    for (int c=0;c<40;++c) acc[c] = 0.f;
    #pragma unroll
    for (int d=0;d<16;++d){
        float v = nw[d];
        #pragma unroll
        for (int c=0;c<40;++c) acc[c] += v * sW[d*40+c];
    }
    float4 ob[10];
    #pragma unroll
    for (int c=0;c<40;++c) ((float*)ob)[c] = rinv*acc[c] + sb[c];
    float4* op = (float4*)(out + (size_t)n*40);
    #pragma unroll
    for (int j=0;j<10;++j) op[j] = ob[j];
}

extern "C" void kernel_launch(void* const* d_in, const int* in_sizes, int n_in,
                              void* d_out, int out_size, void* d_ws, size_t ws_size,
                              hipStream_t stream){
    (void)n_in; (void)out_size; (void)ws_size;
    const float* H  = (const float*)d_in[0];
    const float* W1 = (const float*)d_in[1];
    const float* b1 = (const float*)d_in[2];
    const float* W2 = (const float*)d_in[3];
    const float* b2 = (const float*)d_in[4];
    const int* edges = (const int*)d_in[5];
    float* out = (float*)d_out;

    const int N = in_sizes[0] / 128;   // 200000
    const int E = in_sizes[5] / 16;    // 40000
    const int total = E * 16;          // 640000
    const int total8 = N * 128 / 8;    // 3.2M

    char* ws = (char*)d_ws;
    size_t off = 0;
    // region A: CH (live until fused_l1), later reused for X + ES2s
    _Float16* CH   = (_Float16*)(ws + off);
    _Float16* X    = (_Float16*)(ws + off);                              //  6.40 MB (over CH)
    _Float16* ES2s = (_Float16*)(ws + off + (size_t)N*16*sizeof(_Float16)); // 1.28 MB
    off += (size_t)N*128*sizeof(_Float16);                               // 51.20 MB
    _Float16* ES1s = (_Float16*)(ws + off); off += (size_t)E*128*sizeof(_Float16); // 10.24 MB
    int* cnt = (int*)(ws + off); off += (size_t)N*sizeof(int);           //  0.80 MB
    unsigned short* lists = (unsigned short*)(ws + off);
    off += (size_t)N*CAP*sizeof(unsigned short);                         // 12.80 MB

    hipMemsetAsync(cnt, 0, (size_t)N*sizeof(int), stream);
    ch_stream<<<2048, 256, 0, stream>>>(H, CH, total8);
    build_lists<<<(total+255)/256, 256, 0, stream>>>(edges, cnt, lists, total);
    es_l1<<<(E+3)/4, 256, 0, stream>>>(CH, edges, ES1s, E);
    fused_l1<<<(N+7)/8, 256, 0, stream>>>(CH, ES1s, cnt, lists, W1, b1, X, N);
    es_l2<<<(E*8+255)/256, 256, 0, stream>>>(X, edges, ES2s, E);
    node_l2<<<(N+255)/256, 256, 0, stream>>>(X, ES2s, cnt, lists, W2, b2, out, N);
}